// Round 6
// baseline (430.771 us; speedup 1.0000x reference)
//
#include <hip/hip_runtime.h>
#include <hip/hip_bf16.h>
#include <cstdint>
#include <cstddef>

// Problem constants
constexpr int B_  = 2;
constexpr int T_  = 2048;
constexpr int D_  = 2048;
constexpr int H_  = 8;
constexpr int HD_ = 128;
constexpr int C_  = 1024;   // H*HD
constexpr int BT_ = 64;
constexpr int NT_ = 32;     // T/BT
constexpr int M_  = 4096;   // B*T
constexpr float EPS_RMS = 1.1920929e-07f;

typedef __bf16 bf16x8 __attribute__((ext_vector_type(8)));
typedef float f32x4 __attribute__((ext_vector_type(4)));

typedef const __attribute__((address_space(1))) unsigned int* gptr_t;
typedef __attribute__((address_space(3))) unsigned int* lptr_t;

__device__ __forceinline__ void gload16(const void* g, void* l) {
  __builtin_amdgcn_global_load_lds((gptr_t)g, (lptr_t)l, 16, 0, 0);
}

// ---------------------------------------------------------------------------
// bf16 MFMA GEMM (m97 structure): C[M,N] = A[M,K] @ Bt[N,K]^T  (unchanged)
// ---------------------------------------------------------------------------
template <typename OutT>
__global__ __launch_bounds__(256) void gemm_bf16k(
    const __hip_bfloat16* __restrict__ A, const __hip_bfloat16* __restrict__ Bt,
    OutT* __restrict__ C, int N, int K) {
  __shared__ __hip_bfloat16 sA[128 * 32];
  __shared__ __hip_bfloat16 sB[128 * 32];
  const int tid = threadIdx.x;
  const int lane = tid & 63;
  const int m0 = blockIdx.y * 128, n0 = blockIdx.x * 128;
  const int wm = ((tid >> 6) >> 1) * 64, wn = ((tid >> 6) & 1) * 64;
  f32x4 acc[4][4];
#pragma unroll
  for (int i = 0; i < 4; ++i)
#pragma unroll
    for (int j = 0; j < 4; ++j) acc[i][j] = (f32x4)(0.f);
  const int f0 = tid, f1 = tid + 256;
  const int r0 = f0 >> 2, c0 = (f0 & 3) * 8;
  const int r1 = f1 >> 2, c1 = (f1 & 3) * 8;
  const size_t aoff0 = (size_t)(m0 + r0) * K + c0;
  const size_t aoff1 = (size_t)(m0 + r1) * K + c1;
  const size_t boff0 = (size_t)(n0 + r0) * K + c0;
  const size_t boff1 = (size_t)(n0 + r1) * K + c1;
  const int lr = lane & 15, lk = (lane >> 4) * 8;
  for (int k0 = 0; k0 < K; k0 += 32) {
    __syncthreads();
    gload16(A + aoff0 + k0, &sA[f0 * 8]);
    gload16(A + aoff1 + k0, &sA[f1 * 8]);
    gload16(Bt + boff0 + k0, &sB[f0 * 8]);
    gload16(Bt + boff1 + k0, &sB[f1 * 8]);
    __syncthreads();
    bf16x8 af[4], bfr[4];
#pragma unroll
    for (int i = 0; i < 4; ++i)
      af[i] = *(const bf16x8*)&sA[(wm + i * 16 + lr) * 32 + lk];
#pragma unroll
    for (int j = 0; j < 4; ++j)
      bfr[j] = *(const bf16x8*)&sB[(wn + j * 16 + lr) * 32 + lk];
#pragma unroll
    for (int i = 0; i < 4; ++i)
#pragma unroll
      for (int j = 0; j < 4; ++j)
        acc[i][j] = __builtin_amdgcn_mfma_f32_16x16x32_bf16(af[i], bfr[j], acc[i][j], 0, 0, 0);
  }
  const int er = (lane >> 4) * 4, ec = lane & 15;
#pragma unroll
  for (int i = 0; i < 4; ++i) {
#pragma unroll
    for (int j = 0; j < 4; ++j) {
      int row = m0 + wm + i * 16 + er;
      int col = n0 + wn + j * 16 + ec;
#pragma unroll
      for (int r = 0; r < 4; ++r) {
        float v = acc[i][j][r];
        if constexpr (sizeof(OutT) == 2)
          C[(size_t)(row + r) * N + col] = __float2bfloat16(v);
        else
          C[(size_t)(row + r) * N + col] = v;
      }
    }
  }
}

__global__ __launch_bounds__(256) void gemm_bf16_sk(
    const __hip_bfloat16* __restrict__ A, const __hip_bfloat16* __restrict__ Bt,
    float* __restrict__ Cp, int N, int K, int KS) {
  __shared__ __hip_bfloat16 sA[128 * 32];
  __shared__ __hip_bfloat16 sB[128 * 32];
  const int tid = threadIdx.x;
  const int lane = tid & 63;
  const int m0 = blockIdx.y * 128, n0 = blockIdx.x * 128;
  const int wm = ((tid >> 6) >> 1) * 64, wn = ((tid >> 6) & 1) * 64;
  const int kb = blockIdx.z * KS;
  float* Cs = Cp + (size_t)blockIdx.z * ((size_t)gridDim.y * 128) * N;
  f32x4 acc[4][4];
#pragma unroll
  for (int i = 0; i < 4; ++i)
#pragma unroll
    for (int j = 0; j < 4; ++j) acc[i][j] = (f32x4)(0.f);
  const int f0 = tid, f1 = tid + 256;
  const int r0 = f0 >> 2, c0 = (f0 & 3) * 8;
  const int r1 = f1 >> 2, c1 = (f1 & 3) * 8;
  const size_t aoff0 = (size_t)(m0 + r0) * K + c0;
  const size_t aoff1 = (size_t)(m0 + r1) * K + c1;
  const size_t boff0 = (size_t)(n0 + r0) * K + c0;
  const size_t boff1 = (size_t)(n0 + r1) * K + c1;
  const int lr = lane & 15, lk = (lane >> 4) * 8;
  for (int k0 = kb; k0 < kb + KS; k0 += 32) {
    __syncthreads();
    gload16(A + aoff0 + k0, &sA[f0 * 8]);
    gload16(A + aoff1 + k0, &sA[f1 * 8]);
    gload16(Bt + boff0 + k0, &sB[f0 * 8]);
    gload16(Bt + boff1 + k0, &sB[f1 * 8]);
    __syncthreads();
    bf16x8 af[4], bfr[4];
#pragma unroll
    for (int i = 0; i < 4; ++i)
      af[i] = *(const bf16x8*)&sA[(wm + i * 16 + lr) * 32 + lk];
#pragma unroll
    for (int j = 0; j < 4; ++j)
      bfr[j] = *(const bf16x8*)&sB[(wn + j * 16 + lr) * 32 + lk];
#pragma unroll
    for (int i = 0; i < 4; ++i)
#pragma unroll
      for (int j = 0; j < 4; ++j)
        acc[i][j] = __builtin_amdgcn_mfma_f32_16x16x32_bf16(af[i], bfr[j], acc[i][j], 0, 0, 0);
  }
  const int er = (lane >> 4) * 4, ec = lane & 15;
#pragma unroll
  for (int i = 0; i < 4; ++i)
#pragma unroll
    for (int j = 0; j < 4; ++j) {
      int row = m0 + wm + i * 16 + er;
      int col = n0 + wn + j * 16 + ec;
#pragma unroll
      for (int r = 0; r < 4; ++r)
        Cs[(size_t)(row + r) * N + col] = acc[i][j][r];
    }
}

// au / gu projection, z-muxed: z=0: ad@Wau -> a_full f32; z=1: gd@Wgu -> gatef bf16
__global__ __launch_bounds__(256) void gemm_augu(
    const __hip_bfloat16* __restrict__ ad, const __hip_bfloat16* __restrict__ gd,
    const __hip_bfloat16* __restrict__ Wau, const __hip_bfloat16* __restrict__ Wgu,
    float* __restrict__ a_full, __hip_bfloat16* __restrict__ gatef) {
  constexpr int N = 1024, K = 128;
  const int z = blockIdx.z;
  const __hip_bfloat16* A = z ? gd : ad;
  const __hip_bfloat16* Bt = z ? Wgu : Wau;
  __shared__ __hip_bfloat16 sA[128 * 32];
  __shared__ __hip_bfloat16 sB[128 * 32];
  const int tid = threadIdx.x;
  const int lane = tid & 63;
  const int m0 = blockIdx.y * 128, n0 = blockIdx.x * 128;
  const int wm = ((tid >> 6) >> 1) * 64, wn = ((tid >> 6) & 1) * 64;
  f32x4 acc[4][4];
#pragma unroll
  for (int i = 0; i < 4; ++i)
#pragma unroll
    for (int j = 0; j < 4; ++j) acc[i][j] = (f32x4)(0.f);
  const int f0 = tid, f1 = tid + 256;
  const int r0 = f0 >> 2, c0 = (f0 & 3) * 8;
  const int r1 = f1 >> 2, c1 = (f1 & 3) * 8;
  const size_t aoff0 = (size_t)(m0 + r0) * K + c0;
  const size_t aoff1 = (size_t)(m0 + r1) * K + c1;
  const size_t boff0 = (size_t)(n0 + r0) * K + c0;
  const size_t boff1 = (size_t)(n0 + r1) * K + c1;
  const int lr = lane & 15, lk = (lane >> 4) * 8;
#pragma unroll
  for (int k0 = 0; k0 < K; k0 += 32) {
    __syncthreads();
    gload16(A + aoff0 + k0, &sA[f0 * 8]);
    gload16(A + aoff1 + k0, &sA[f1 * 8]);
    gload16(Bt + boff0 + k0, &sB[f0 * 8]);
    gload16(Bt + boff1 + k0, &sB[f1 * 8]);
    __syncthreads();
    bf16x8 af[4], bfr[4];
#pragma unroll
    for (int i = 0; i < 4; ++i)
      af[i] = *(const bf16x8*)&sA[(wm + i * 16 + lr) * 32 + lk];
#pragma unroll
    for (int j = 0; j < 4; ++j)
      bfr[j] = *(const bf16x8*)&sB[(wn + j * 16 + lr) * 32 + lk];
#pragma unroll
    for (int i = 0; i < 4; ++i)
#pragma unroll
      for (int j = 0; j < 4; ++j)
        acc[i][j] = __builtin_amdgcn_mfma_f32_16x16x32_bf16(af[i], bfr[j], acc[i][j], 0, 0, 0);
  }
  const int er = (lane >> 4) * 4, ec = lane & 15;
#pragma unroll
  for (int i = 0; i < 4; ++i)
#pragma unroll
    for (int j = 0; j < 4; ++j) {
      int row = m0 + wm + i * 16 + er;
      int col = n0 + wn + j * 16 + ec;
#pragma unroll
      for (int r = 0; r < 4; ++r) {
        float v = acc[i][j][r];
        if (z == 0) a_full[(size_t)(row + r) * N + col] = v;
        else        gatef[(size_t)(row + r) * N + col] = __float2bfloat16(v);
      }
    }
}

__global__ __launch_bounds__(256) void reduce_dg(
    const float* __restrict__ slabs, __hip_bfloat16* __restrict__ adb,
    __hip_bfloat16* __restrict__ gdb) {
  int idx = blockIdx.x * 256 + threadIdx.x;
  int m = idx >> 8, c = idx & 255;
  const size_t ss = (size_t)M_ * 256;
  float s = slabs[idx] + slabs[idx + ss] + slabs[idx + 2 * ss] + slabs[idx + 3 * ss];
  if (c < 128) adb[(size_t)m * 128 + c] = __float2bfloat16(s);
  else         gdb[(size_t)m * 128 + (c - 128)] = __float2bfloat16(s);
}

__global__ __launch_bounds__(256) void cvt_bf(
    const float* __restrict__ in, __hip_bfloat16* __restrict__ out) {
  size_t i = ((size_t)blockIdx.x * 256 + threadIdx.x) * 4;
  float4 v = *(const float4*)(in + i);
  out[i + 0] = __float2bfloat16(v.x);
  out[i + 1] = __float2bfloat16(v.y);
  out[i + 2] = __float2bfloat16(v.z);
  out[i + 3] = __float2bfloat16(v.w);
}

// Transpose-convert with z-multiplexing: up to 3 sources, contiguous dsts.
__global__ __launch_bounds__(256) void tconv_z(
    const float* __restrict__ W0, const float* __restrict__ W1,
    const float* __restrict__ W2, __hip_bfloat16* __restrict__ Wt, int K, int N) {
  const float* W = (blockIdx.z == 0) ? W0 : (blockIdx.z == 1) ? W1 : W2;
  __hip_bfloat16* dst = Wt + (size_t)blockIdx.z * K * N;
  __shared__ float tile[32][33];
  int tx = threadIdx.x & 31, ty = threadIdx.x >> 5;
  int kb = blockIdx.y * 32, nb = blockIdx.x * 32;
#pragma unroll
  for (int s = 0; s < 4; ++s) {
    int kk = ty + s * 8;
    tile[kk][tx] = W[(size_t)(kb + kk) * N + nb + tx];
  }
  __syncthreads();
#pragma unroll
  for (int s = 0; s < 4; ++s) {
    int nn = ty + s * 8;
    dst[(size_t)(nb + nn) * K + kb + tx] = __float2bfloat16(tile[tx][nn]);
  }
}

// ---------------------------------------------------------------------------
// conv_chunk: per (b,h,n) chunk — gate cumsum (glast out), q/k/v conv +
// L2norm/silu + exp scaling, bf16 head-layout outputs.  LDS ~50 KB.
// ---------------------------------------------------------------------------
__global__ __launch_bounds__(256) void conv_chunk(
    const __hip_bfloat16* __restrict__ pre, const float* __restrict__ a_full,
    const float* __restrict__ cqw, const float* __restrict__ cqb,
    const float* __restrict__ ckw, const float* __restrict__ ckb,
    const float* __restrict__ cvw, const float* __restrict__ cvb,
    __hip_bfloat16* __restrict__ qg, __hip_bfloat16* __restrict__ kp,
    __hip_bfloat16* __restrict__ km, __hip_bfloat16* __restrict__ vb,
    float* __restrict__ glast) {
  __shared__ float gcS[64][128];
  __shared__ __align__(16) __hip_bfloat16 raw[67 * 128];
  __shared__ float red[64][2];
  const int tid = threadIdx.x;
  const int bhn = blockIdx.x;
  const int bh = bhn >> 5, n = bhn & 31;
  const int b = bh >> 3, h = bh & 7;
  const int t0 = n * 64, hoff = h * 128;
  const size_t gbase = ((size_t)bh * T_ + t0) * 128;

  // Phase A: gate cumsum
  for (int ci = tid; ci < 2048; ci += 256) {
    int r = ci >> 5, c4 = (ci & 31) * 4;
    *(float4*)&gcS[r][c4] =
        *(const float4*)(a_full + (size_t)(b * T_ + t0 + r) * C_ + hoff + c4);
  }
  __syncthreads();
  if (tid < 128) {
    float run = 0.f;
    for (int i = 0; i < 64; ++i) {
      float a = gcS[i][tid];
      float s = fmaxf(1.f / (1.f + __expf(-a)), 1e-6f);
      run += __logf(s);
      gcS[i][tid] = run;
    }
    glast[(size_t)bhn * 128 + tid] = run;
  }
  __syncthreads();

  const int d = tid & 127, r2 = tid >> 7;
  const int c = hoff + d;
  const int half = (tid >> 6) & 1;

  // Phase B: k conv + L2 norm + exp scaling -> kp, km
  for (int ci = tid; ci < 1072; ci += 256) {
    int rr = ci >> 4, c8 = (ci & 15) * 8;
    int gt = t0 - 3 + rr;
    uint4 val = make_uint4(0, 0, 0, 0);
    if (gt >= 0)
      val = *(const uint4*)(pre + (size_t)(b * T_ + gt) * (3 * C_) + C_ + hoff + c8);
    *(uint4*)&raw[rr * 128 + c8] = val;
  }
  __syncthreads();
  {
    const float w0 = ckw[c * 4 + 0], w1 = ckw[c * 4 + 1];
    const float w2 = ckw[c * 4 + 2], w3 = ckw[c * 4 + 3];
    const float bia = ckb[c];
    float cv[32];
#pragma unroll
    for (int i = 0; i < 32; ++i) {
      int r = 2 * i + r2;
      float acc = bia + w0 * __bfloat162float(raw[(r + 0) * 128 + d])
                      + w1 * __bfloat162float(raw[(r + 1) * 128 + d])
                      + w2 * __bfloat162float(raw[(r + 2) * 128 + d])
                      + w3 * __bfloat162float(raw[(r + 3) * 128 + d]);
      cv[i] = acc;
      float ss = acc * acc;
#pragma unroll
      for (int o = 1; o < 64; o <<= 1) ss += __shfl_xor(ss, o);
      if ((tid & 63) == 0) red[r][half] = ss;
    }
    __syncthreads();
#pragma unroll
    for (int i = 0; i < 32; ++i) {
      int r = 2 * i + r2;
      float inv = 1.f / fmaxf(sqrtf(red[r][0] + red[r][1]), 1e-12f);
      float g = gcS[r][d];
      float kn = cv[i] * inv;
      kp[gbase + (size_t)r * 128 + d] = __float2bfloat16(kn * __expf(g));
      km[gbase + (size_t)r * 128 + d] = __float2bfloat16(kn * __expf(-g));
    }
  }
  __syncthreads();

  // Phase C: q conv + L2 norm + exp scaling -> qg
  for (int ci = tid; ci < 1072; ci += 256) {
    int rr = ci >> 4, c8 = (ci & 15) * 8;
    int gt = t0 - 3 + rr;
    uint4 val = make_uint4(0, 0, 0, 0);
    if (gt >= 0)
      val = *(const uint4*)(pre + (size_t)(b * T_ + gt) * (3 * C_) + hoff + c8);
    *(uint4*)&raw[rr * 128 + c8] = val;
  }
  __syncthreads();
  {
    const float w0 = cqw[c * 4 + 0], w1 = cqw[c * 4 + 1];
    const float w2 = cqw[c * 4 + 2], w3 = cqw[c * 4 + 3];
    const float bia = cqb[c];
    float cv[32];
#pragma unroll
    for (int i = 0; i < 32; ++i) {
      int r = 2 * i + r2;
      float acc = bia + w0 * __bfloat162float(raw[(r + 0) * 128 + d])
                      + w1 * __bfloat162float(raw[(r + 1) * 128 + d])
                      + w2 * __bfloat162float(raw[(r + 2) * 128 + d])
                      + w3 * __bfloat162float(raw[(r + 3) * 128 + d]);
      cv[i] = acc;
      float ss = acc * acc;
#pragma unroll
      for (int o = 1; o < 64; o <<= 1) ss += __shfl_xor(ss, o);
      if ((tid & 63) == 0) red[r][half] = ss;
    }
    __syncthreads();
#pragma unroll
    for (int i = 0; i < 32; ++i) {
      int r = 2 * i + r2;
      float inv = 1.f / fmaxf(sqrtf(red[r][0] + red[r][1]), 1e-12f);
      float g = gcS[r][d];
      qg[gbase + (size_t)r * 128 + d] = __float2bfloat16(cv[i] * inv * __expf(g));
    }
  }
  __syncthreads();

  // Phase D: v conv + silu -> vb
  for (int ci = tid; ci < 1072; ci += 256) {
    int rr = ci >> 4, c8 = (ci & 15) * 8;
    int gt = t0 - 3 + rr;
    uint4 val = make_uint4(0, 0, 0, 0);
    if (gt >= 0)
      val = *(const uint4*)(pre + (size_t)(b * T_ + gt) * (3 * C_) + 2 * C_ + hoff + c8);
    *(uint4*)&raw[rr * 128 + c8] = val;
  }
  __syncthreads();
  {
    const float w0 = cvw[c * 4 + 0], w1 = cvw[c * 4 + 1];
    const float w2 = cvw[c * 4 + 2], w3 = cvw[c * 4 + 3];
    const float bia = cvb[c];
#pragma unroll
    for (int i = 0; i < 32; ++i) {
      int r = 2 * i + r2;
      float acc = bia + w0 * __bfloat162float(raw[(r + 0) * 128 + d])
                      + w1 * __bfloat162float(raw[(r + 1) * 128 + d])
                      + w2 * __bfloat162float(raw[(r + 2) * 128 + d])
                      + w3 * __bfloat162float(raw[(r + 3) * 128 + d]);
      vb[gbase + (size_t)r * 128 + d] =
          __float2bfloat16(acc * (1.f / (1.f + __expf(-acc))));
    }
  }
}

// ---------------------------------------------------------------------------
// chunk_mid: MFMA pairdot (Akk -> LDS transposed, Aq -> global bf16),
// dual-rhs register forward substitution (w & u in one thread), ppre
// PT_bf[vd][kd] = bf16(sum_i u[i][vd]*km[i][kd]).  LDS ~50 KB.
// ---------------------------------------------------------------------------
__global__ __launch_bounds__(256) void chunk_mid(
    const __hip_bfloat16* __restrict__ qg, const __hip_bfloat16* __restrict__ kp,
    const __hip_bfloat16* __restrict__ km, const __hip_bfloat16* __restrict__ vb,
    __hip_bfloat16* __restrict__ Aq, __hip_bfloat16* __restrict__ w_bf,
    __hip_bfloat16* __restrict__ u_bf, __hip_bfloat16* __restrict__ PT_bf) {
  __shared__ float A_T[64][68];     // A_T[i][j] = Akk[j][i]
  __shared__ float solu[64][128];
  const int tid = threadIdx.x;
  const int bhn = blockIdx.x;
  const size_t gbase = ((size_t)(bhn >> 5) * T_ + (size_t)(bhn & 31) * BT_) * HD_;
  const int wv = tid >> 6, lane = tid & 63;
  const int lr = lane & 15, lg = lane >> 4;
  const int prod = wv >> 1, rh = wv & 1;

  // Phase 1: MFMA pair products.
  {
    const __hip_bfloat16* A = (prod ? qg : km) + gbase;
    const __hip_bfloat16* Bt = (prod ? km : kp) + gbase;
    f32x4 acc[2][4];
#pragma unroll
    for (int i = 0; i < 2; ++i)
#pragma unroll
      for (int j = 0; j < 4; ++j) acc[i][j] = (f32x4)(0.f);
#pragma unroll
    for (int k0 = 0; k0 < 128; k0 += 32) {
      bf16x8 af[2], bfr[4];
#pragma unroll
      for (int i = 0; i < 2; ++i)
        af[i] = *(const bf16x8*)(A + (size_t)(rh * 32 + i * 16 + lr) * 128 + k0 + lg * 8);
#pragma unroll
      for (int j = 0; j < 4; ++j)
        bfr[j] = *(const bf16x8*)(Bt + (size_t)(j * 16 + lr) * 128 + k0 + lg * 8);
#pragma unroll
      for (int i = 0; i < 2; ++i)
#pragma unroll
        for (int j = 0; j < 4; ++j)
          acc[i][j] = __builtin_amdgcn_mfma_f32_16x16x32_bf16(af[i], bfr[j], acc[i][j], 0, 0, 0);
    }
    if (prod == 0) {
#pragma unroll
      for (int i = 0; i < 2; ++i)
#pragma unroll
        for (int j = 0; j < 4; ++j) {
          int row0 = rh * 32 + i * 16 + lg * 4;
          int col = j * 16 + lr;
          *(float4*)&A_T[col][row0] =
              make_float4(acc[i][j][0], acc[i][j][1], acc[i][j][2], acc[i][j][3]);
        }
    } else {
      __hip_bfloat16* dst = Aq + (size_t)bhn * 4096;
#pragma unroll
      for (int i = 0; i < 2; ++i)
#pragma unroll
        for (int j = 0; j < 4; ++j)
#pragma unroll
          for (int r = 0; r < 4; ++r) {
            int row = rh * 32 + i * 16 + lg * 4 + r;
            int col = j * 16 + lr;
            float v = (col <= row) ? acc[i][j][r] : 0.f;
            dst[row * 64 + col] = __float2bfloat16(v);
          }
    }
  }
  __syncthreads();

  // Phase 2: dual-rhs register-resident forward substitution (unit lower).
  // Threads 0-127 each solve BOTH w (rhs kp) and u (rhs v) for one column;
  // halves the broadcast A_T LDS traffic vs one-rhs-per-thread.
  if (tid < 128) {
    const int col = tid;
    const __hip_bfloat16* rw = kp + gbase;
    const __hip_bfloat16* ru = vb + gbase;
    float sw[64], su[64];
#pragma unroll
    for (int i = 0; i < 64; ++i) {
      sw[i] = __bfloat162float(rw[(size_t)i * 128 + col]);
      su[i] = __bfloat162float(ru[(size_t)i * 128 + col]);
    }
#pragma unroll
    for (int i = 0; i < 63; ++i) {
      const float siw = sw[i], siu = su[i];
      const int j0 = (i + 1) & ~3;
#pragma unroll
      for (int j4 = j0; j4 < 64; j4 += 4) {
        float4 a4 = *(const float4*)&A_T[i][j4];
        if (j4 > i)     { sw[j4]     -= a4.x * siw; su[j4]     -= a4.x * siu; }
        if (j4 + 1 > i) { sw[j4 + 1] -= a4.y * siw; su[j4 + 1] -= a4.y * siu; }
        if (j4 + 2 > i) { sw[j4 + 2] -= a4.z * siw; su[j4 + 2] -= a4.z * siu; }
        if (j4 + 3 > i) { sw[j4 + 3] -= a4.w * siw; su[j4 + 3] -= a4.w * siu; }
      }
    }
#pragma unroll
    for (int i = 0; i < 64; ++i) {
      w_bf[gbase + (size_t)i * 128 + col] = __float2bfloat16(sw[i]);
      u_bf[gbase + (size_t)i * 128 + col] = __float2bfloat16(su[i]);
      solu[i][col] = su[i];
    }
  }
  __syncthreads();

  // Phase 3: ppre — PT_bf[vd][kd] = bf16(sum_i solu[i][vd] * km[i][kd])
  {
    const int kd0 = (tid >> 4) * 8, vd0 = (tid & 15) * 8;
    float acc[8][8];
#pragma unroll
    for (int a = 0; a < 8; ++a)
#pragma unroll
      for (int b2 = 0; b2 < 8; ++b2) acc[a][b2] = 0.f;
    for (int i = 0; i < 64; ++i) {
      uint4 rawv = *(const uint4*)(km + gbase + (size_t)i * 128 + kd0);
      const __hip_bfloat16* hp = (const __hip_bfloat16*)&rawv;
      float kv[8];
#pragma unroll
      for (int e = 0; e < 8; ++e) kv[e] = __bfloat162float(hp[e]);
      float uv[8];
      *(float4*)(uv)     = *(const float4*)&solu[i][vd0];
      *(float4*)(uv + 4) = *(const float4*)&solu[i][vd0 + 4];
#pragma unroll
      for (int a = 0; a < 8; ++a)
#pragma unroll
        for (int b2 = 0; b2 < 8; ++b2) acc[a][b2] = fmaf(kv[a], uv[b2], acc[a][b2]);
    }
    __hip_bfloat16* dst = PT_bf + (size_t)bhn * 16384;
#pragma unroll
    for (int b2 = 0; b2 < 8; ++b2) {
      union { __hip_bfloat16 hx[8]; uint4 u4; } pk;
#pragma unroll
      for (int a = 0; a < 8; ++a) pk.hx[a] = __float2bfloat16(acc[a][b2]);
      *(uint4*)(dst + (size_t)(vd0 + b2) * 128 + kd0) = pk.u4;
    }
  }
}

// ---------------------------------------------------------------------------
// scan over chunks on PT layout (bf16 in, f32 accumulate):
// STg[n] = bf16(state BEFORE chunk n); final -> Sout[bh][kd][vd] (f32).
// ---------------------------------------------------------------------------
__global__ __launch_bounds__(128) void scan_pt(
    const __hip_bfloat16* __restrict__ PT_bf, const float* __restrict__ glast,
    __hip_bfloat16* __restrict__ STg, float* __restrict__ Sout) {
  int vd = blockIdx.x & 127;
  int bh = blockIdx.x >> 7;
  int kd = threadIdx.x;
  float s = 0.f;
  for (int n = 0; n < NT_; ++n) {
    size_t idx = (((size_t)bh * NT_ + n) * HD_ + vd) * HD_ + kd;
    float p = __bfloat162float(PT_bf[idx]);
    STg[idx] = __float2bfloat16(s);
    float gl = glast[((size_t)bh * NT_ + n) * 128 + kd];
    s = (s + p) * __expf(gl);
  }
  Sout[((size_t)bh * HD_ + kd) * HD_ + vd] = s;
}

// ---------------------------------------------------------------------------
// chunk_tail: MFMA accX=w@S, accO=qg@S (S frags direct from global bf16 STg),
// X=u-accX (transposed bf16 to LDS), MFMA accO+=Aq@X, RMS+gate epilogue.
// ---------------------------------------------------------------------------
__global__ __launch_bounds__(256) void chunk_tail(
    const __hip_bfloat16* __restrict__ qg_bf, const __hip_bfloat16* __restrict__ w_bf,
    const __hip_bfloat16* __restrict__ u_bf, const __hip_bfloat16* __restrict__ Aq_bf,
    const __hip_bfloat16* __restrict__ STg, const __hip_bfloat16* __restrict__ gatef,
    const float* __restrict__ normw, __hip_bfloat16* __restrict__ o2b) {
  constexpr int XTS = 72;
  __shared__ __hip_bfloat16 XT[128 * XTS];
  __shared__ float red[64][4];
  const int tid = threadIdx.x;
  const int bhn = blockIdx.x;
  const int bh = bhn >> 5, n = bhn & 31;
  const int b = bh >> 3, h = bh & 7;
  const int t0 = n * 64, hoff = h * 128;
  const size_t gbase = ((size_t)bh * T_ + t0) * 128;
  const __hip_bfloat16* Sg = STg + (size_t)bhn * 16384;

  const int wv = tid >> 6, lane = tid & 63;
  const int lr = lane & 15, lg = lane >> 4;
  f32x4 accX[4][2], accO[4][2];
#pragma unroll
  for (int i = 0; i < 4; ++i)
#pragma unroll
    for (int j = 0; j < 2; ++j) { accX[i][j] = (f32x4)(0.f); accO[i][j] = (f32x4)(0.f); }

  const __hip_bfloat16* wrow = w_bf + gbase;
  const __hip_bfloat16* qrow = qg_bf + gbase;
#pragma unroll
  for (int k0 = 0; k0 < 128; k0 += 32) {
    bf16x8 aW[4], aQ[4], bS[2];
#pragma unroll
    for (int i = 0; i < 4; ++i) {
      aW[i] = *(const bf16x8*)(wrow + (size_t)(i * 16 + lr) * 128 + k0 + lg * 8);
      aQ[i] = *(const bf16x8*)(qrow + (size_t)(i * 16 + lr) * 128 + k0 + lg * 8);
    }
#pragma unroll
    for (int j = 0; j < 2; ++j)
      bS[j] = *(const bf16x8*)(Sg + (size_t)(wv * 32 + j * 16 + lr) * 128 + k0 + lg * 8);
#pragma unroll
    for (int i = 0; i < 4; ++i)
#pragma unroll
      for (int j = 0; j < 2; ++j) {
        accX[i][j] = __builtin_amdgcn_mfma_f32_16x16x32_bf16(aW[i], bS[j], accX[i][j], 0, 0, 0);
        accO[i][j] = __builtin_amdgcn_mfma_f32_16x16x32_bf16(aQ[i], bS[j], accO[i][j], 0, 0, 0);
      }
  }

  // X = u - accX, transposed bf16 to XT
#pragma unroll
  for (int i = 0; i < 4; ++i)
#pragma unroll
    for (int j = 0; j < 2; ++j) {
      int row0 = i * 16 + lg * 4;
      int col = wv * 32 + j * 16 + lr;
      union { __hip_bfloat16 hx[4]; uint2 u2; } xv;
#pragma unroll
      for (int r = 0; r < 4; ++r) {
        float uu = __bfloat162float(u_bf[gbase + (size_t)(row0 + r) * 128 + col]);
        xv.hx[r] = __float2bfloat16(uu - accX[i][j][r]);
      }
      *(uint2*)&XT[col * XTS + row0] = xv.u2;
    }
  __syncthreads();

  // accO += Aq @ X
  const __hip_bfloat16* aqb = Aq_bf + (size_t)bhn * 4096;
#pragma unroll
  for (int k0 = 0; k0 < 64; k0 += 32) {
    bf16x8 aA[4], bX[2];
#pragma unroll
    for (int i = 0; i < 4; ++i)
      aA[i] = *(const bf16x8*)(aqb + (size_t)(i * 16 + lr) * 64 + k0 + lg * 8);
#pragma unroll
    for (int j = 0; j < 2; ++j)
      bX[j] = *(const bf16x8*)&XT[(wv * 32 + j * 16 + lr) * XTS + k0 + lg * 8];
#pragma unroll
    for (int i = 0; i < 4; ++i)
#pragma unroll
      for (int j = 0; j < 2; ++j)
        accO[i][j] = __builtin_amdgcn_mfma_f32_16x16x32_bf16(aA[i], bX[j], accO[i][j], 0, 0, 0);
  }

  // RMS + gate epilogue
#pragma unroll
  for (int i = 0; i < 4; ++i)
#pragma unroll
    for (int r = 0; r < 4; ++r) {
      int row = i * 16 + lg * 4 + r;
      float o0 = accO[i][0][r], o1 = accO[i][1][r];
      float ss = o0 * o0 + o1 * o1;
#pragma unroll
      for (int o = 1; o < 16; o <<= 1) ss += __shfl_xor(ss, o);
      if (lr == 0) red[row][wv] = ss;
    }
  __syncthreads();
  float nw0 = normw[wv * 32 + lr];
  float nw1 = normw[wv * 32 + 16 + lr];
#pragma unroll
  for (int i = 0; i < 4; ++i)
#pragma unroll
    for (int r = 0; r < 4; ++r) {
      int row = i * 16 + lg * 4 + r;
      float tot = red[row][0] + red[row][1] + red[row][2] + red[row][3];
      float rms = rsqrtf(tot * (1.f / 128.f) + EPS_RMS);
      size_t orow = (size_t)(b * T_ + t0 + row) * C_ + hoff;
      int c0 = wv * 32 + lr, c1 = c0 + 16;
      float g0 = __bfloat162float(gatef[orow + c0]);
      float g1 = __bfloat162float(gatef[orow + c1]);
      float s0 = 1.f / (1.f + __expf(-g0));
      float s1 = 1.f / (1.f + __expf(-g1));
      o2b[orow + c0] = __float2bfloat16(accO[i][0][r] * rms * nw0 * s0);
      o2b[orow + c1] = __float2bfloat16(accO[i][1][r] * rms * nw1 * s1);
    }
}

// ---------------------------------------------------------------------------
extern "C" void kernel_launch(void* const* d_in, const int* in_sizes, int n_in,
                              void* d_out, int out_size, void* d_ws, size_t ws_size,
                              hipStream_t stream) {
  (void)in_sizes; (void)n_in; (void)out_size;
  const float* x    = (const float*)d_in[0];
  const float* Wq   = (const float*)d_in[1];
  const float* Wk   = (const float*)d_in[2];
  const float* Wv   = (const float*)d_in[3];
  const float* cqw  = (const float*)d_in[4];
  const float* cqb  = (const float*)d_in[5];
  const float* ckw  = (const float*)d_in[6];
  const float* ckb  = (const float*)d_in[7];
  const float* cvw  = (const float*)d_in[8];
  const float* cvb  = (const float*)d_in[9];
  const float* Wad  = (const float*)d_in[10];
  const float* Wau  = (const float*)d_in[11];
  // d_in[12] = Wb : dead code in reference
  const float* Wgd  = (const float*)d_in[13];
  const float* Wgu  = (const float*)d_in[14];
  const float* normw= (const float*)d_in[15];
  const float* Wo   = (const float*)d_in[16];

  float* outp = (float*)d_out;
  float* Sout = outp + (size_t)M_ * D_;

  const size_t SZ = (size_t)M_ * C_;  // 4,194,304 f32 units

  float* ws = (float*)d_ws;
  __hip_bfloat16* pre_qkv = (__hip_bfloat16*)(ws);                 // 1.5 SZ
  float* a_full = ws + 3 * SZ / 2;                                  // 1 SZ
  __hip_bfloat16* gatef = (__hip_bfloat16*)(ws + 5 * SZ / 2);       // 0.5 SZ
  __hip_bfloat16* qg_bf = (__hip_bfloat16*)(ws + 3 * SZ);           // 0.5 SZ
  __hip_bfloat16* kp_bf = (__hip_bfloat16*)(ws + 7 * SZ / 2);       // 0.5 SZ
  __hip_bfloat16* km_bf = (__hip_bfloat16*)(ws + 4 * SZ);           // 0.5 SZ
  __hip_bfloat16* v_bf  = (__hip_bfloat16*)(ws + 9 * SZ / 2);       // 0.5 SZ
  __hip_bfloat16* w_bf  = (__hip_bfloat16*)(ws + 5 * SZ);           // 0.5 SZ
  __hip_bfloat16* u_bf  = (__hip_bfloat16*)(ws + 11 * SZ / 2);      // 0.5 SZ
  __hip_bfloat16* Aq_bf = (__hip_bfloat16*)(ws + 6 * SZ);           // 0.25 SZ
  float* glast = ws + 25 * SZ / 4;                                  // 65536 units
  __hip_bfloat16* PT_bf = (__hip_bfloat16*)(ws + 13 * SZ / 2);      // 1 SZ (bf16 8.4M)
  __hip_bfloat16* STg   = (__hip_bfloat16*)(ws + 15 * SZ / 2);      // 1 SZ
  __hip_bfloat16* xb    = (__hip_bfloat16*)(ws + 17 * SZ / 2);      // 1 SZ
  __hip_bfloat16* Wt_qkv = (__hip_bfloat16*)(ws + 19 * SZ / 2);     // 0.75 SZ
  size_t off = 19 * SZ / 2 + 3 * SZ / 4;
  __hip_bfloat16* Wt_dg  = (__hip_bfloat16*)(ws + off); off += 262144;
  __hip_bfloat16* Wt_aug = (__hip_bfloat16*)(ws + off); off += 131072;
  __hip_bfloat16* Wt_o   = (__hip_bfloat16*)(ws + off); off += 1048576;
  __hip_bfloat16* ad_bf  = (__hip_bfloat16*)(ws + off); off += 262144;
  __hip_bfloat16* gd_bf  = (__hip_bfloat16*)(ws + off); off += 262144;
  if (ws_size < off * sizeof(float)) return;

  float* slabs = ws + 13 * SZ / 2;                // alias PT_bf region (dead before chunk_mid)
  __hip_bfloat16* o2b = (__hip_bfloat16*)a_full;  // a_full dead after conv_chunk
  __hip_bfloat16* Wt_au = Wt_aug;
  __hip_bfloat16* Wt_gu = Wt_aug + (size_t)C_ * HD_;

  // Phase 0: bf16 conversions
  cvt_bf<<<(int)((size_t)M_ * D_ / 1024), 256, 0, stream>>>(x, xb);
  tconv_z<<<dim3(C_ / 32, D_ / 32, 3), 256, 0, stream>>>(Wq, Wk, Wv, Wt_qkv, D_, C_);
  tconv_z<<<dim3(HD_ / 32, D_ / 32, 2), 256, 0, stream>>>(Wad, Wgd, Wgd, Wt_dg, D_, HD_);
  tconv_z<<<dim3(C_ / 32, HD_ / 32, 2), 256, 0, stream>>>(Wau, Wgu, Wgu, Wt_aug, HD_, C_);
  tconv_z<<<dim3(D_ / 32, C_ / 32, 1), 256, 0, stream>>>(Wo, Wo, Wo, Wt_o, C_, D_);

  // Phase 1: projections (MFMA bf16)
  gemm_bf16k<__hip_bfloat16><<<dim3(3 * C_ / 128, M_ / 128), 256, 0, stream>>>(
      xb, Wt_qkv, pre_qkv, 3 * C_, D_);
  gemm_bf16_sk<<<dim3(2, M_ / 128, 4), 256, 0, stream>>>(xb, Wt_dg, slabs, 256, D_, D_ / 4);
  reduce_dg<<<(int)((size_t)M_ * 256 / 256), 256, 0, stream>>>(slabs, ad_bf, gd_bf);
  gemm_augu<<<dim3(C_ / 128, M_ / 128, 2), 256, 0, stream>>>(
      ad_bf, gd_bf, Wt_au, Wt_gu, a_full, gatef);

  // Phase 2: fused gate cumsum + q/k/v conv
  conv_chunk<<<B_ * H_ * NT_, 256, 0, stream>>>(pre_qkv, a_full, cqw, cqb, ckw, ckb,
                                                cvw, cvb, qg_bf, kp_bf, km_bf, v_bf, glast);

  // Phase 3: fused pairdot + solve + ppre, then state scan
  chunk_mid<<<B_ * H_ * NT_, 256, 0, stream>>>(qg_bf, kp_bf, km_bf, v_bf,
                                               Aq_bf, w_bf, u_bf, PT_bf);
  scan_pt<<<B_ * H_ * HD_, 128, 0, stream>>>(PT_bf, glast, STg, Sout);

  // Phase 4: fused output tail + projection
  chunk_tail<<<B_ * H_ * NT_, 256, 0, stream>>>(qg_bf, w_bf, u_bf, Aq_bf, STg,
                                                gatef, normw, o2b);
  gemm_bf16k<float><<<dim3(D_ / 128, M_ / 128), 256, 0, stream>>>(o2b, Wt_o, outp, D_, C_);
}

// Round 7
// 397.503 us; speedup vs baseline: 1.0837x; 1.0837x over previous
//
#include <hip/hip_runtime.h>
#include <hip/hip_bf16.h>
#include <cstdint>
#include <cstddef>

// Problem constants
constexpr int B_  = 2;
constexpr int T_  = 2048;
constexpr int D_  = 2048;
constexpr int H_  = 8;
constexpr int HD_ = 128;
constexpr int C_  = 1024;   // H*HD
constexpr int BT_ = 64;
constexpr int NT_ = 32;     // T/BT
constexpr int M_  = 4096;   // B*T
constexpr float EPS_RMS = 1.1920929e-07f;

typedef __bf16 bf16x8 __attribute__((ext_vector_type(8)));
typedef float f32x4 __attribute__((ext_vector_type(4)));

typedef const __attribute__((address_space(1))) unsigned int* gptr_t;
typedef __attribute__((address_space(3))) unsigned int* lptr_t;

__device__ __forceinline__ void gload16(const void* g, void* l) {
  __builtin_amdgcn_global_load_lds((gptr_t)g, (lptr_t)l, 16, 0, 0);
}

// ---------------------------------------------------------------------------
// bf16 MFMA GEMM (m97 structure): C[M,N] = A[M,K] @ Bt[N,K]^T
// ---------------------------------------------------------------------------
template <typename OutT>
__global__ __launch_bounds__(256) void gemm_bf16k(
    const __hip_bfloat16* __restrict__ A, const __hip_bfloat16* __restrict__ Bt,
    OutT* __restrict__ C, int N, int K) {
  __shared__ __hip_bfloat16 sA[128 * 32];
  __shared__ __hip_bfloat16 sB[128 * 32];
  const int tid = threadIdx.x;
  const int lane = tid & 63;
  const int m0 = blockIdx.y * 128, n0 = blockIdx.x * 128;
  const int wm = ((tid >> 6) >> 1) * 64, wn = ((tid >> 6) & 1) * 64;
  f32x4 acc[4][4];
#pragma unroll
  for (int i = 0; i < 4; ++i)
#pragma unroll
    for (int j = 0; j < 4; ++j) acc[i][j] = (f32x4)(0.f);
  const int f0 = tid, f1 = tid + 256;
  const int r0 = f0 >> 2, c0 = (f0 & 3) * 8;
  const int r1 = f1 >> 2, c1 = (f1 & 3) * 8;
  const size_t aoff0 = (size_t)(m0 + r0) * K + c0;
  const size_t aoff1 = (size_t)(m0 + r1) * K + c1;
  const size_t boff0 = (size_t)(n0 + r0) * K + c0;
  const size_t boff1 = (size_t)(n0 + r1) * K + c1;
  const int lr = lane & 15, lk = (lane >> 4) * 8;
  for (int k0 = 0; k0 < K; k0 += 32) {
    __syncthreads();
    gload16(A + aoff0 + k0, &sA[f0 * 8]);
    gload16(A + aoff1 + k0, &sA[f1 * 8]);
    gload16(Bt + boff0 + k0, &sB[f0 * 8]);
    gload16(Bt + boff1 + k0, &sB[f1 * 8]);
    __syncthreads();
    bf16x8 af[4], bfr[4];
#pragma unroll
    for (int i = 0; i < 4; ++i)
      af[i] = *(const bf16x8*)&sA[(wm + i * 16 + lr) * 32 + lk];
#pragma unroll
    for (int j = 0; j < 4; ++j)
      bfr[j] = *(const bf16x8*)&sB[(wn + j * 16 + lr) * 32 + lk];
#pragma unroll
    for (int i = 0; i < 4; ++i)
#pragma unroll
      for (int j = 0; j < 4; ++j)
        acc[i][j] = __builtin_amdgcn_mfma_f32_16x16x32_bf16(af[i], bfr[j], acc[i][j], 0, 0, 0);
  }
  const int er = (lane >> 4) * 4, ec = lane & 15;
#pragma unroll
  for (int i = 0; i < 4; ++i) {
#pragma unroll
    for (int j = 0; j < 4; ++j) {
      int row = m0 + wm + i * 16 + er;
      int col = n0 + wn + j * 16 + ec;
#pragma unroll
      for (int r = 0; r < 4; ++r) {
        float v = acc[i][j][r];
        if constexpr (sizeof(OutT) == 2)
          C[(size_t)(row + r) * N + col] = __float2bfloat16(v);
        else
          C[(size_t)(row + r) * N + col] = v;
      }
    }
  }
}

// ---------------------------------------------------------------------------
// gemm_p1: merged launch.  bid<768: qkv projection tile (M=4096,N=3072,K=2048,
// bf16 out).  bid>=768: split-K dg projection (N=256, K-slab 512, f32 slabs).
// ---------------------------------------------------------------------------
__global__ __launch_bounds__(256) void gemm_p1(
    const __hip_bfloat16* __restrict__ xb, const __hip_bfloat16* __restrict__ Wt_qkv,
    const __hip_bfloat16* __restrict__ Wt_dg, __hip_bfloat16* __restrict__ pre_qkv,
    float* __restrict__ slabs) {
  __shared__ __hip_bfloat16 sA[128 * 32];
  __shared__ __hip_bfloat16 sB[128 * 32];
  const int bid = blockIdx.x;
  const int tid = threadIdx.x;
  const int lane = tid & 63;
  const bool isqkv = bid < 768;
  int m0, n0, kb, ke, N, z = 0;
  const __hip_bfloat16* Bt;
  if (isqkv) {
    n0 = (bid % 24) * 128; m0 = (bid / 24) * 128;
    kb = 0; ke = 2048; N = 3072; Bt = Wt_qkv;
  } else {
    int s = bid - 768;
    n0 = (s & 1) * 128; m0 = ((s >> 1) & 31) * 128;
    z = s >> 6;
    kb = z * 512; ke = kb + 512; N = 256; Bt = Wt_dg;
  }
  const int K = 2048;
  const int wm = ((tid >> 6) >> 1) * 64, wn = ((tid >> 6) & 1) * 64;
  f32x4 acc[4][4];
#pragma unroll
  for (int i = 0; i < 4; ++i)
#pragma unroll
    for (int j = 0; j < 4; ++j) acc[i][j] = (f32x4)(0.f);
  const int f0 = tid, f1 = tid + 256;
  const int r0 = f0 >> 2, c0 = (f0 & 3) * 8;
  const int r1 = f1 >> 2, c1 = (f1 & 3) * 8;
  const size_t aoff0 = (size_t)(m0 + r0) * K + c0;
  const size_t aoff1 = (size_t)(m0 + r1) * K + c1;
  const size_t boff0 = (size_t)(n0 + r0) * K + c0;
  const size_t boff1 = (size_t)(n0 + r1) * K + c1;
  const int lr = lane & 15, lk = (lane >> 4) * 8;
  for (int k0 = kb; k0 < ke; k0 += 32) {
    __syncthreads();
    gload16(xb + aoff0 + k0, &sA[f0 * 8]);
    gload16(xb + aoff1 + k0, &sA[f1 * 8]);
    gload16(Bt + boff0 + k0, &sB[f0 * 8]);
    gload16(Bt + boff1 + k0, &sB[f1 * 8]);
    __syncthreads();
    bf16x8 af[4], bfr[4];
#pragma unroll
    for (int i = 0; i < 4; ++i)
      af[i] = *(const bf16x8*)&sA[(wm + i * 16 + lr) * 32 + lk];
#pragma unroll
    for (int j = 0; j < 4; ++j)
      bfr[j] = *(const bf16x8*)&sB[(wn + j * 16 + lr) * 32 + lk];
#pragma unroll
    for (int i = 0; i < 4; ++i)
#pragma unroll
      for (int j = 0; j < 4; ++j)
        acc[i][j] = __builtin_amdgcn_mfma_f32_16x16x32_bf16(af[i], bfr[j], acc[i][j], 0, 0, 0);
  }
  const int er = (lane >> 4) * 4, ec = lane & 15;
  if (isqkv) {
#pragma unroll
    for (int i = 0; i < 4; ++i)
#pragma unroll
      for (int j = 0; j < 4; ++j) {
        int row = m0 + wm + i * 16 + er;
        int col = n0 + wn + j * 16 + ec;
#pragma unroll
        for (int r = 0; r < 4; ++r)
          pre_qkv[(size_t)(row + r) * N + col] = __float2bfloat16(acc[i][j][r]);
      }
  } else {
    float* Cs = slabs + (size_t)z * M_ * 256;
#pragma unroll
    for (int i = 0; i < 4; ++i)
#pragma unroll
      for (int j = 0; j < 4; ++j) {
        int row = m0 + wm + i * 16 + er;
        int col = n0 + wn + j * 16 + ec;
#pragma unroll
        for (int r = 0; r < 4; ++r)
          Cs[(size_t)(row + r) * N + col] = acc[i][j][r];
      }
  }
}

// au / gu projection, z-muxed: z=0: ad@Wau -> a_full f32; z=1: gd@Wgu -> gatef bf16
__global__ __launch_bounds__(256) void gemm_augu(
    const __hip_bfloat16* __restrict__ ad, const __hip_bfloat16* __restrict__ gd,
    const __hip_bfloat16* __restrict__ Wau, const __hip_bfloat16* __restrict__ Wgu,
    float* __restrict__ a_full, __hip_bfloat16* __restrict__ gatef) {
  constexpr int N = 1024, K = 128;
  const int z = blockIdx.z;
  const __hip_bfloat16* A = z ? gd : ad;
  const __hip_bfloat16* Bt = z ? Wgu : Wau;
  __shared__ __hip_bfloat16 sA[128 * 32];
  __shared__ __hip_bfloat16 sB[128 * 32];
  const int tid = threadIdx.x;
  const int lane = tid & 63;
  const int m0 = blockIdx.y * 128, n0 = blockIdx.x * 128;
  const int wm = ((tid >> 6) >> 1) * 64, wn = ((tid >> 6) & 1) * 64;
  f32x4 acc[4][4];
#pragma unroll
  for (int i = 0; i < 4; ++i)
#pragma unroll
    for (int j = 0; j < 4; ++j) acc[i][j] = (f32x4)(0.f);
  const int f0 = tid, f1 = tid + 256;
  const int r0 = f0 >> 2, c0 = (f0 & 3) * 8;
  const int r1 = f1 >> 2, c1 = (f1 & 3) * 8;
  const size_t aoff0 = (size_t)(m0 + r0) * K + c0;
  const size_t aoff1 = (size_t)(m0 + r1) * K + c1;
  const size_t boff0 = (size_t)(n0 + r0) * K + c0;
  const size_t boff1 = (size_t)(n0 + r1) * K + c1;
  const int lr = lane & 15, lk = (lane >> 4) * 8;
#pragma unroll
  for (int k0 = 0; k0 < K; k0 += 32) {
    __syncthreads();
    gload16(A + aoff0 + k0, &sA[f0 * 8]);
    gload16(A + aoff1 + k0, &sA[f1 * 8]);
    gload16(Bt + boff0 + k0, &sB[f0 * 8]);
    gload16(Bt + boff1 + k0, &sB[f1 * 8]);
    __syncthreads();
    bf16x8 af[4], bfr[4];
#pragma unroll
    for (int i = 0; i < 4; ++i)
      af[i] = *(const bf16x8*)&sA[(wm + i * 16 + lr) * 32 + lk];
#pragma unroll
    for (int j = 0; j < 4; ++j)
      bfr[j] = *(const bf16x8*)&sB[(wn + j * 16 + lr) * 32 + lk];
#pragma unroll
    for (int i = 0; i < 4; ++i)
#pragma unroll
      for (int j = 0; j < 4; ++j)
        acc[i][j] = __builtin_amdgcn_mfma_f32_16x16x32_bf16(af[i], bfr[j], acc[i][j], 0, 0, 0);
  }
  const int er = (lane >> 4) * 4, ec = lane & 15;
#pragma unroll
  for (int i = 0; i < 4; ++i)
#pragma unroll
    for (int j = 0; j < 4; ++j) {
      int row = m0 + wm + i * 16 + er;
      int col = n0 + wn + j * 16 + ec;
#pragma unroll
      for (int r = 0; r < 4; ++r) {
        float v = acc[i][j][r];
        if (z == 0) a_full[(size_t)(row + r) * N + col] = v;
        else        gatef[(size_t)(row + r) * N + col] = __float2bfloat16(v);
      }
    }
}

__global__ __launch_bounds__(256) void reduce_dg(
    const float* __restrict__ slabs, __hip_bfloat16* __restrict__ adb,
    __hip_bfloat16* __restrict__ gdb) {
  int idx = blockIdx.x * 256 + threadIdx.x;
  int m = idx >> 8, c = idx & 255;
  const size_t ss = (size_t)M_ * 256;
  float s = slabs[idx] + slabs[idx + ss] + slabs[idx + 2 * ss] + slabs[idx + 3 * ss];
  if (c < 128) adb[(size_t)m * 128 + c] = __float2bfloat16(s);
  else         gdb[(size_t)m * 128 + (c - 128)] = __float2bfloat16(s);
}

// ---------------------------------------------------------------------------
// prep: merged cvt_bf (x -> xb) + all weight transpose-conversions.
// Flat grid of 17152 blocks, 256 threads.
// ---------------------------------------------------------------------------
__global__ __launch_bounds__(256) void prep(
    const float* __restrict__ x, const float* __restrict__ Wq,
    const float* __restrict__ Wk, const float* __restrict__ Wv,
    const float* __restrict__ Wad, const float* __restrict__ Wgd,
    const float* __restrict__ Wau, const float* __restrict__ Wgu,
    const float* __restrict__ Wo, __hip_bfloat16* __restrict__ xb,
    __hip_bfloat16* __restrict__ Wt_qkv, __hip_bfloat16* __restrict__ Wt_dg,
    __hip_bfloat16* __restrict__ Wt_aug, __hip_bfloat16* __restrict__ Wt_o) {
  __shared__ float tile[32][33];
  int bid = blockIdx.x;
  const int tid = threadIdx.x;
  if (bid < 8192) {
    size_t i = ((size_t)bid * 256 + tid) * 4;
    float4 v = *(const float4*)(x + i);
    xb[i + 0] = __float2bfloat16(v.x);
    xb[i + 1] = __float2bfloat16(v.y);
    xb[i + 2] = __float2bfloat16(v.z);
    xb[i + 3] = __float2bfloat16(v.w);
    return;
  }
  bid -= 8192;
  const float* W; __hip_bfloat16* dst; int K, N, bx, by;
  if (bid < 6144) {
    int z = bid / 2048, r = bid % 2048;
    W = (z == 0) ? Wq : (z == 1) ? Wk : Wv;
    dst = Wt_qkv + (size_t)z * C_ * D_;
    K = D_; N = C_; bx = r & 31; by = r >> 5;
  } else if (bid < 6144 + 512) {
    int b2 = bid - 6144;
    int z = b2 >> 8, r = b2 & 255;
    W = z ? Wgd : Wad;
    dst = Wt_dg + (size_t)z * HD_ * D_;
    K = D_; N = HD_; bx = r & 3; by = r >> 2;
  } else if (bid < 6144 + 512 + 256) {
    int b2 = bid - 6144 - 512;
    int z = b2 >> 7, r = b2 & 127;
    W = z ? Wgu : Wau;
    dst = Wt_aug + (size_t)z * C_ * HD_;
    K = HD_; N = C_; bx = r & 31; by = r >> 5;
  } else {
    int b2 = bid - 6144 - 512 - 256;
    W = Wo; dst = Wt_o;
    K = C_; N = D_; bx = b2 & 63; by = b2 >> 6;
  }
  int tx = tid & 31, ty = tid >> 5;
  int kb = by * 32, nb = bx * 32;
#pragma unroll
  for (int s = 0; s < 4; ++s) {
    int kk = ty + s * 8;
    tile[kk][tx] = W[(size_t)(kb + kk) * N + nb + tx];
  }
  __syncthreads();
#pragma unroll
  for (int s = 0; s < 4; ++s) {
    int nn = ty + s * 8;
    dst[(size_t)(nb + nn) * K + kb + tx] = __float2bfloat16(tile[tx][nn]);
  }
}

// ---------------------------------------------------------------------------
// gc: per (b,h,n) chunk, LDS-staged cumsum; writes full gc + chunk-last row.
// ---------------------------------------------------------------------------
__global__ __launch_bounds__(256) void gc_lds(
    const float* __restrict__ a_full, float* __restrict__ gc,
    float* __restrict__ glast) {
  __shared__ float gcS[64][128];
  const int tid = threadIdx.x;
  const int bhn = blockIdx.x;
  const int bh = bhn >> 5, n = bhn & 31;
  const int b = bh >> 3, h = bh & 7;
  const int t0 = n * 64, hoff = h * 128;
  for (int ci = tid; ci < 2048; ci += 256) {
    int r = ci >> 5, c4 = (ci & 31) * 4;
    *(float4*)&gcS[r][c4] =
        *(const float4*)(a_full + (size_t)(b * T_ + t0 + r) * C_ + hoff + c4);
  }
  __syncthreads();
  if (tid < 128) {
    float run = 0.f;
    for (int i = 0; i < 64; ++i) {
      float a = gcS[i][tid];
      float s = fmaxf(1.f / (1.f + __expf(-a)), 1e-6f);
      run += __logf(s);
      gcS[i][tid] = run;
    }
    glast[(size_t)bhn * 128 + tid] = run;
  }
  __syncthreads();
  const size_t gbase = ((size_t)bh * T_ + t0) * 128;
  for (int ci = tid; ci < 2048; ci += 256) {
    int r = ci >> 5, c4 = (ci & 31) * 4;
    *(float4*)(gc + gbase + r * 128 + c4) = *(const float4*)&gcS[r][c4];
  }
}

// ---------------------------------------------------------------------------
// Fused q/k/v conv (window 4) + norms/silu + exp scaling; bf16 head-layout out.
// grid = B*T*H (h fastest), 128 threads.   (R5-verified form)
// ---------------------------------------------------------------------------
__global__ __launch_bounds__(128) void conv_qkv(
    const __hip_bfloat16* __restrict__ pre, const float* __restrict__ gc,
    const float* __restrict__ cqw, const float* __restrict__ cqb,
    const float* __restrict__ ckw, const float* __restrict__ ckb,
    const float* __restrict__ cvw, const float* __restrict__ cvb,
    __hip_bfloat16* __restrict__ qg, __hip_bfloat16* __restrict__ kp,
    __hip_bfloat16* __restrict__ km, __hip_bfloat16* __restrict__ vb) {
  int idx = blockIdx.x;
  int h = idx & 7;
  int t = (idx >> 3) & (T_ - 1);
  int b = idx >> 14;
  int d = threadIdx.x;
  int c = h * HD_ + d;
  const __hip_bfloat16* p = pre + (size_t)(b * T_ + t) * (3 * C_) + c;
  float aq, ak, av;
  {
    float w0 = cqw[c * 4], w1 = cqw[c * 4 + 1], w2 = cqw[c * 4 + 2], w3 = cqw[c * 4 + 3];
    aq = cqb[c] + w3 * __bfloat162float(p[0]);
    if (t > 0) aq += w2 * __bfloat162float(p[-(ptrdiff_t)(3 * C_)]);
    if (t > 1) aq += w1 * __bfloat162float(p[-2 * (ptrdiff_t)(3 * C_)]);
    if (t > 2) aq += w0 * __bfloat162float(p[-3 * (ptrdiff_t)(3 * C_)]);
  }
  {
    const __hip_bfloat16* pk = p + C_;
    float w0 = ckw[c * 4], w1 = ckw[c * 4 + 1], w2 = ckw[c * 4 + 2], w3 = ckw[c * 4 + 3];
    ak = ckb[c] + w3 * __bfloat162float(pk[0]);
    if (t > 0) ak += w2 * __bfloat162float(pk[-(ptrdiff_t)(3 * C_)]);
    if (t > 1) ak += w1 * __bfloat162float(pk[-2 * (ptrdiff_t)(3 * C_)]);
    if (t > 2) ak += w0 * __bfloat162float(pk[-3 * (ptrdiff_t)(3 * C_)]);
  }
  {
    const __hip_bfloat16* pv = p + 2 * C_;
    float w0 = cvw[c * 4], w1 = cvw[c * 4 + 1], w2 = cvw[c * 4 + 2], w3 = cvw[c * 4 + 3];
    av = cvb[c] + w3 * __bfloat162float(pv[0]);
    if (t > 0) av += w2 * __bfloat162float(pv[-(ptrdiff_t)(3 * C_)]);
    if (t > 1) av += w1 * __bfloat162float(pv[-2 * (ptrdiff_t)(3 * C_)]);
    if (t > 2) av += w0 * __bfloat162float(pv[-3 * (ptrdiff_t)(3 * C_)]);
  }
  float ssq = aq * aq, ssk = ak * ak;
#pragma unroll
  for (int o = 1; o < 64; o <<= 1) {
    ssq += __shfl_xor(ssq, o);
    ssk += __shfl_xor(ssk, o);
  }
  __shared__ float red[2][2];
  if ((d & 63) == 0) { red[0][d >> 6] = ssq; red[1][d >> 6] = ssk; }
  __syncthreads();
  float nq = fmaxf(sqrtf(red[0][0] + red[0][1]), 1e-12f);
  float nk = fmaxf(sqrtf(red[1][0] + red[1][1]), 1e-12f);
  size_t oi = (((size_t)b * H_ + h) * T_ + t) * HD_ + d;
  float g = gc[oi];
  float eg = __expf(g), emg = __expf(-g);
  qg[oi] = __float2bfloat16(aq / nq * eg);
  float kn = ak / nk;
  kp[oi] = __float2bfloat16(kn * eg);
  km[oi] = __float2bfloat16(kn * emg);
  vb[oi] = __float2bfloat16(av * (1.f / (1.f + __expf(-av))));
}

// ---------------------------------------------------------------------------
// chunk_mid: MFMA pairdot (Akk -> LDS transposed, Aq -> global bf16),
// 256-thread register forward substitution (R5 form), ppre -> PT bf16.
// ---------------------------------------------------------------------------
__global__ __launch_bounds__(256) void chunk_mid(
    const __hip_bfloat16* __restrict__ qg, const __hip_bfloat16* __restrict__ kp,
    const __hip_bfloat16* __restrict__ km, const __hip_bfloat16* __restrict__ vb,
    __hip_bfloat16* __restrict__ Aq, __hip_bfloat16* __restrict__ w_bf,
    __hip_bfloat16* __restrict__ u_bf, __hip_bfloat16* __restrict__ PT_bf) {
  __shared__ float A_T[64][68];     // A_T[i][j] = Akk[j][i]
  __shared__ float solu[64][128];
  const int tid = threadIdx.x;
  const int bhn = blockIdx.x;
  const size_t gbase = ((size_t)(bhn >> 5) * T_ + (size_t)(bhn & 31) * BT_) * HD_;
  const int wv = tid >> 6, lane = tid & 63;
  const int lr = lane & 15, lg = lane >> 4;
  const int prod = wv >> 1, rh = wv & 1;

  // Phase 1: MFMA pair products.
  {
    const __hip_bfloat16* A = (prod ? qg : km) + gbase;
    const __hip_bfloat16* Bt = (prod ? km : kp) + gbase;
    f32x4 acc[2][4];
#pragma unroll
    for (int i = 0; i < 2; ++i)
#pragma unroll
      for (int j = 0; j < 4; ++j) acc[i][j] = (f32x4)(0.f);
#pragma unroll
    for (int k0 = 0; k0 < 128; k0 += 32) {
      bf16x8 af[2], bfr[4];
#pragma unroll
      for (int i = 0; i < 2; ++i)
        af[i] = *(const bf16x8*)(A + (size_t)(rh * 32 + i * 16 + lr) * 128 + k0 + lg * 8);
#pragma unroll
      for (int j = 0; j < 4; ++j)
        bfr[j] = *(const bf16x8*)(Bt + (size_t)(j * 16 + lr) * 128 + k0 + lg * 8);
#pragma unroll
      for (int i = 0; i < 2; ++i)
#pragma unroll
        for (int j = 0; j < 4; ++j)
          acc[i][j] = __builtin_amdgcn_mfma_f32_16x16x32_bf16(af[i], bfr[j], acc[i][j], 0, 0, 0);
    }
    if (prod == 0) {
#pragma unroll
      for (int i = 0; i < 2; ++i)
#pragma unroll
        for (int j = 0; j < 4; ++j) {
          int row0 = rh * 32 + i * 16 + lg * 4;
          int col = j * 16 + lr;
          *(float4*)&A_T[col][row0] =
              make_float4(acc[i][j][0], acc[i][j][1], acc[i][j][2], acc[i][j][3]);
        }
    } else {
      __hip_bfloat16* dst = Aq + (size_t)bhn * 4096;
#pragma unroll
      for (int i = 0; i < 2; ++i)
#pragma unroll
        for (int j = 0; j < 4; ++j)
#pragma unroll
          for (int r = 0; r < 4; ++r) {
            int row = rh * 32 + i * 16 + lg * 4 + r;
            int col = j * 16 + lr;
            float v = (col <= row) ? acc[i][j][r] : 0.f;
            dst[row * 64 + col] = __float2bfloat16(v);
          }
    }
  }
  __syncthreads();

  // Phase 2: register-resident forward substitution, one rhs column/thread
  // (R5 form: threads 0-127 -> w from kp; 128-255 -> u from v).
  {
    const int col = tid & 127;
    const __hip_bfloat16* rhs = ((tid < 128) ? kp : vb) + gbase;
    float s[64];
#pragma unroll
    for (int i = 0; i < 64; ++i)
      s[i] = __bfloat162float(rhs[(size_t)i * 128 + col]);
#pragma unroll
    for (int i = 0; i < 63; ++i) {
      const float si = s[i];
      const int j0 = (i + 1) & ~3;
#pragma unroll
      for (int j4 = j0; j4 < 64; j4 += 4) {
        float4 a4 = *(const float4*)&A_T[i][j4];
        if (j4 > i)     s[j4]     -= a4.x * si;
        if (j4 + 1 > i) s[j4 + 1] -= a4.y * si;
        if (j4 + 2 > i) s[j4 + 2] -= a4.z * si;
        if (j4 + 3 > i) s[j4 + 3] -= a4.w * si;
      }
    }
    if (tid < 128) {
#pragma unroll
      for (int i = 0; i < 64; ++i)
        w_bf[gbase + (size_t)i * 128 + col] = __float2bfloat16(s[i]);
    } else {
#pragma unroll
      for (int i = 0; i < 64; ++i) {
        u_bf[gbase + (size_t)i * 128 + col] = __float2bfloat16(s[i]);
        solu[i][col] = s[i];
      }
    }
  }
  __syncthreads();

  // Phase 3: ppre — PT_bf[vd][kd] = bf16(sum_i solu[i][vd] * km[i][kd])
  {
    const int kd0 = (tid >> 4) * 8, vd0 = (tid & 15) * 8;
    float acc[8][8];
#pragma unroll
    for (int a = 0; a < 8; ++a)
#pragma unroll
      for (int b2 = 0; b2 < 8; ++b2) acc[a][b2] = 0.f;
    for (int i = 0; i < 64; ++i) {
      uint4 rawv = *(const uint4*)(km + gbase + (size_t)i * 128 + kd0);
      const __hip_bfloat16* hp = (const __hip_bfloat16*)&rawv;
      float kv[8];
#pragma unroll
      for (int e = 0; e < 8; ++e) kv[e] = __bfloat162float(hp[e]);
      float uv[8];
      *(float4*)(uv)     = *(const float4*)&solu[i][vd0];
      *(float4*)(uv + 4) = *(const float4*)&solu[i][vd0 + 4];
#pragma unroll
      for (int a = 0; a < 8; ++a)
#pragma unroll
        for (int b2 = 0; b2 < 8; ++b2) acc[a][b2] = fmaf(kv[a], uv[b2], acc[a][b2]);
    }
    __hip_bfloat16* dst = PT_bf + (size_t)bhn * 16384;
#pragma unroll
    for (int b2 = 0; b2 < 8; ++b2) {
      union { __hip_bfloat16 hx[8]; uint4 u4; } pk2;
#pragma unroll
      for (int a = 0; a < 8; ++a) pk2.hx[a] = __float2bfloat16(acc[a][b2]);
      *(uint4*)(dst + (size_t)(vd0 + b2) * 128 + kd0) = pk2.u4;
    }
  }
}

// ---------------------------------------------------------------------------
// scan over chunks on PT layout (bf16 in, f32 accumulate):
// STg[n] = bf16(state BEFORE chunk n); final -> Sout[bh][kd][vd] (f32).
// ---------------------------------------------------------------------------
__global__ __launch_bounds__(128) void scan_pt(
    const __hip_bfloat16* __restrict__ PT_bf, const float* __restrict__ glast,
    __hip_bfloat16* __restrict__ STg, float* __restrict__ Sout) {
  int vd = blockIdx.x & 127;
  int bh = blockIdx.x >> 7;
  int kd = threadIdx.x;
  float s = 0.f;
  for (int n = 0; n < NT_; ++n) {
    size_t idx = (((size_t)bh * NT_ + n) * HD_ + vd) * HD_ + kd;
    float p = __bfloat162float(PT_bf[idx]);
    STg[idx] = __float2bfloat16(s);
    float gl = glast[((size_t)bh * NT_ + n) * 128 + kd];
    s = (s + p) * __expf(gl);
  }
  Sout[((size_t)bh * HD_ + kd) * HD_ + vd] = s;
}

// ---------------------------------------------------------------------------
// chunk_tail: MFMA accX=w@S, accO=qg@S (S frags direct from global bf16 STg),
// X=u-accX (transposed bf16 to LDS), MFMA accO+=Aq@X, RMS+gate epilogue.
// ---------------------------------------------------------------------------
__global__ __launch_bounds__(256) void chunk_tail(
    const __hip_bfloat16* __restrict__ qg_bf, const __hip_bfloat16* __restrict__ w_bf,
    const __hip_bfloat16* __restrict__ u_bf, const __hip_bfloat16* __restrict__ Aq_bf,
    const __hip_bfloat16* __restrict__ STg, const __hip_bfloat16* __restrict__ gatef,
    const float* __restrict__ normw, __hip_bfloat16* __restrict__ o2b) {
  constexpr int XTS = 72;
  __shared__ __hip_bfloat16 XT[128 * XTS];
  __shared__ float red[64][4];
  const int tid = threadIdx.x;
  const int bhn = blockIdx.x;
  const int bh = bhn >> 5, n = bhn & 31;
  const int b = bh >> 3, h = bh & 7;
  const int t0 = n * 64, hoff = h * 128;
  const size_t gbase = ((size_t)bh * T_ + t0) * 128;
  const __hip_bfloat16* Sg = STg + (size_t)bhn * 16384;

  const int wv = tid >> 6, lane = tid & 63;
  const int lr = lane & 15, lg = lane >> 4;
  f32x4 accX[4][2], accO[4][2];
#pragma unroll
  for (int i = 0; i < 4; ++i)
#pragma unroll
    for (int j = 0; j < 2; ++j) { accX[i][j] = (f32x4)(0.f); accO[i][j] = (f32x4)(0.f); }

  const __hip_bfloat16* wrow = w_bf + gbase;
  const __hip_bfloat16* qrow = qg_bf + gbase;
#pragma unroll
  for (int k0 = 0; k0 < 128; k0 += 32) {
    bf16x8 aW[4], aQ[4], bS[2];
#pragma unroll
    for (int i = 0; i < 4; ++i) {
      aW[i] = *(const bf16x8*)(wrow + (size_t)(i * 16 + lr) * 128 + k0 + lg * 8);
      aQ[i] = *(const bf16x8*)(qrow + (size_t)(i * 16 + lr) * 128 + k0 + lg * 8);
    }
#pragma unroll
    for (int j = 0; j < 2; ++j)
      bS[j] = *(const bf16x8*)(Sg + (size_t)(wv * 32 + j * 16 + lr) * 128 + k0 + lg * 8);
#pragma unroll
    for (int i = 0; i < 4; ++i)
#pragma unroll
      for (int j = 0; j < 2; ++j) {
        accX[i][j] = __builtin_amdgcn_mfma_f32_16x16x32_bf16(aW[i], bS[j], accX[i][j], 0, 0, 0);
        accO[i][j] = __builtin_amdgcn_mfma_f32_16x16x32_bf16(aQ[i], bS[j], accO[i][j], 0, 0, 0);
      }
  }

  // X = u - accX, transposed bf16 to XT
#pragma unroll
  for (int i = 0; i < 4; ++i)
#pragma unroll
    for (int j = 0; j < 2; ++j) {
      int row0 = i * 16 + lg * 4;
      int col = wv * 32 + j * 16 + lr;
      union { __hip_bfloat16 hx[4]; uint2 u2; } xv;
#pragma unroll
      for (int r = 0; r < 4; ++r) {
        float uu = __bfloat162float(u_bf[gbase + (size_t)(row0 + r) * 128 + col]);
        xv.hx[r] = __float2bfloat16(uu - accX[i][j][r]);
      }
      *(uint2*)&XT[col * XTS + row0] = xv.u2;
    }
  __syncthreads();

  // accO += Aq @ X
  const __hip_bfloat16* aqb = Aq_bf + (size_t)bhn * 4096;
#pragma unroll
  for (int k0 = 0; k0 < 64; k0 += 32) {
    bf16x8 aA[4], bX[2];
#pragma unroll
    for (int i = 0; i < 4; ++i)
      aA[i] = *(const bf16x8*)(aqb + (size_t)(i * 16 + lr) * 64 + k0 + lg * 8);
#pragma unroll
    for (int j = 0; j < 2; ++j)
      bX[j] = *(const bf16x8*)&XT[(wv * 32 + j * 16 + lr) * XTS + k0 + lg * 8];
#pragma unroll
    for (int i = 0; i < 4; ++i)
#pragma unroll
      for (int j = 0; j < 2; ++j)
        accO[i][j] = __builtin_amdgcn_mfma_f32_16x16x32_bf16(aA[i], bX[j], accO[i][j], 0, 0, 0);
  }

  // RMS + gate epilogue
#pragma unroll
  for (int i = 0; i < 4; ++i)
#pragma unroll
    for (int r = 0; r < 4; ++r) {
      int row = i * 16 + lg * 4 + r;
      float o0 = accO[i][0][r], o1 = accO[i][1][r];
      float ss = o0 * o0 + o1 * o1;
#pragma unroll
      for (int o = 1; o < 16; o <<= 1) ss += __shfl_xor(ss, o);
      if (lr == 0) red[row][wv] = ss;
    }
  __syncthreads();
  float nw0 = normw[wv * 32 + lr];
  float nw1 = normw[wv * 32 + 16 + lr];
#pragma unroll
  for (int i = 0; i < 4; ++i)
#pragma unroll
    for (int r = 0; r < 4; ++r) {
      int row = i * 16 + lg * 4 + r;
      float tot = red[row][0] + red[row][1] + red[row][2] + red[row][3];
      float rms = rsqrtf(tot * (1.f / 128.f) + EPS_RMS);
      size_t orow = (size_t)(b * T_ + t0 + row) * C_ + hoff;
      int c0 = wv * 32 + lr, c1 = c0 + 16;
      float g0 = __bfloat162float(gatef[orow + c0]);
      float g1 = __bfloat162float(gatef[orow + c1]);
      float s0 = 1.f / (1.f + __expf(-g0));
      float s1 = 1.f / (1.f + __expf(-g1));
      o2b[orow + c0] = __float2bfloat16(accO[i][0][r] * rms * nw0 * s0);
      o2b[orow + c1] = __float2bfloat16(accO[i][1][r] * rms * nw1 * s1);
    }
}

// ---------------------------------------------------------------------------
extern "C" void kernel_launch(void* const* d_in, const int* in_sizes, int n_in,
                              void* d_out, int out_size, void* d_ws, size_t ws_size,
                              hipStream_t stream) {
  (void)in_sizes; (void)n_in; (void)out_size;
  const float* x    = (const float*)d_in[0];
  const float* Wq   = (const float*)d_in[1];
  const float* Wk   = (const float*)d_in[2];
  const float* Wv   = (const float*)d_in[3];
  const float* cqw  = (const float*)d_in[4];
  const float* cqb  = (const float*)d_in[5];
  const float* ckw  = (const float*)d_in[6];
  const float* ckb  = (const float*)d_in[7];
  const float* cvw  = (const float*)d_in[8];
  const float* cvb  = (const float*)d_in[9];
  const float* Wad  = (const float*)d_in[10];
  const float* Wau  = (const float*)d_in[11];
  // d_in[12] = Wb : dead code in reference
  const float* Wgd  = (const float*)d_in[13];
  const float* Wgu  = (const float*)d_in[14];
  const float* normw= (const float*)d_in[15];
  const float* Wo   = (const float*)d_in[16];

  float* outp = (float*)d_out;
  float* Sout = outp + (size_t)M_ * D_;

  const size_t SZ = (size_t)M_ * C_;  // 4,194,304 f32 units

  float* ws = (float*)d_ws;
  __hip_bfloat16* pre_qkv = (__hip_bfloat16*)(ws);                 // 1.5 SZ
  float* a_full = ws + 3 * SZ / 2;                                  // 1 SZ
  __hip_bfloat16* gatef = (__hip_bfloat16*)(ws + 5 * SZ / 2);       // 0.5 SZ
  float* gc_g = ws + 3 * SZ;                                        // 1 SZ
  __hip_bfloat16* qg_bf = (__hip_bfloat16*)(ws + 4 * SZ);           // 0.5 SZ
  __hip_bfloat16* kp_bf = (__hip_bfloat16*)(ws + 9 * SZ / 2);       // 0.5 SZ
  __hip_bfloat16* km_bf = (__hip_bfloat16*)(ws + 5 * SZ);           // 0.5 SZ
  __hip_bfloat16* v_bf  = (__hip_bfloat16*)(ws + 11 * SZ / 2);      // 0.5 SZ
  __hip_bfloat16* w_bf  = (__hip_bfloat16*)(ws + 6 * SZ);           // 0.5 SZ
  __hip_bfloat16* u_bf  = (__hip_bfloat16*)(ws + 13 * SZ / 2);      // 0.5 SZ
  __hip_bfloat16* Aq_bf = (__hip_bfloat16*)(ws + 7 * SZ);           // 0.25 SZ
  float* glast = ws + 29 * SZ / 4;                                  // 65536 units
  __hip_bfloat16* PT_bf = (__hip_bfloat16*)(ws + 15 * SZ / 2);      // 1 SZ
  __hip_bfloat16* STg   = (__hip_bfloat16*)(ws + 17 * SZ / 2);      // 1 SZ
  __hip_bfloat16* xb    = (__hip_bfloat16*)(ws + 19 * SZ / 2);      // 1 SZ
  __hip_bfloat16* Wt_qkv = (__hip_bfloat16*)(ws + 21 * SZ / 2);     // 0.75 SZ
  size_t off = 21 * SZ / 2 + 3 * SZ / 4;
  __hip_bfloat16* Wt_dg  = (__hip_bfloat16*)(ws + off); off += 262144;
  __hip_bfloat16* Wt_aug = (__hip_bfloat16*)(ws + off); off += 131072;
  __hip_bfloat16* Wt_o   = (__hip_bfloat16*)(ws + off); off += 1048576;
  __hip_bfloat16* ad_bf  = (__hip_bfloat16*)(ws + off); off += 262144;
  __hip_bfloat16* gd_bf  = (__hip_bfloat16*)(ws + off); off += 262144;
  if (ws_size < off * sizeof(float)) return;

  float* slabs = ws + 15 * SZ / 2;                // alias PT_bf region (dead before chunk_mid)
  __hip_bfloat16* o2b = (__hip_bfloat16*)a_full;  // a_full dead after gc_lds
  __hip_bfloat16* Wt_au = Wt_aug;
  __hip_bfloat16* Wt_gu = Wt_aug + (size_t)C_ * HD_;

  // Phase 0: all bf16 conversions in one launch
  prep<<<17152, 256, 0, stream>>>(x, Wq, Wk, Wv, Wad, Wgd, Wau, Wgu, Wo,
                                  xb, Wt_qkv, Wt_dg, Wt_aug, Wt_o);

  // Phase 1: qkv projection + split-K dg projection in one launch
  gemm_p1<<<1024, 256, 0, stream>>>(xb, Wt_qkv, Wt_dg, pre_qkv, slabs);
  reduce_dg<<<(int)((size_t)M_ * 256 / 256), 256, 0, stream>>>(slabs, ad_bf, gd_bf);
  gemm_augu<<<dim3(C_ / 128, M_ / 128, 2), 256, 0, stream>>>(
      ad_bf, gd_bf, Wt_au, Wt_gu, a_full, gatef);

  // Phase 2: gate cumsum, then fused q/k/v conv
  gc_lds<<<B_ * H_ * NT_, 256, 0, stream>>>(a_full, gc_g, glast);
  conv_qkv<<<B_ * T_ * H_, 128, 0, stream>>>(pre_qkv, gc_g, cqw, cqb, ckw, ckb,
                                             cvw, cvb, qg_bf, kp_bf, km_bf, v_bf);

  // Phase 3: fused pairdot + solve + ppre, then state scan
  chunk_mid<<<B_ * H_ * NT_, 256, 0, stream>>>(qg_bf, kp_bf, km_bf, v_bf,
                                               Aq_bf, w_bf, u_bf, PT_bf);
  scan_pt<<<B_ * H_ * HD_, 128, 0, stream>>>(PT_bf, glast, STg, Sout);

  // Phase 4: fused output tail + projection
  chunk_tail<<<B_ * H_ * NT_, 256, 0, stream>>>(qg_bf, w_bf, u_bf, Aq_bf, STg,
                                                gatef, normw, o2b);
  gemm_bf16k<float><<<dim3(D_ / 128, M_ / 128), 256, 0, stream>>>(o2b, Wt_o, outp, D_, C_);
}